// Round 1
// baseline (26697.095 us; speedup 1.0000x reference)
//
#include <hip/hip_runtime.h>
#include <math.h>

// Persistent cooperative LSTM: 256 WGs x 512 threads, 1 WG/CU.
// WG w owns hidden units [8w, 8w+8). wave u = unit, lane group g = gate.
// Weights (folded W' = W_hh + (w1+w2) (x) W_lin) live in VGPRs: 128/thread.
// Per step: local matvec -> local c/h update -> publish 8 floats -> flag ->
// poll 256 flags -> reload full h into LDS. y_t computed by WG (t%256).

#define HDIM 2048
#define TSTEPS 4096
#define NWG 256
#define NTH 512  // 8 waves

__device__ __forceinline__ float sigmoidf_(float x) {
    return 1.0f / (1.0f + expf(-x));
}

__global__ __launch_bounds__(NTH, 2)
void weld_lstm_persistent(const float* __restrict__ src,
                          const float* __restrict__ W_ih,
                          const float* __restrict__ W_hh,
                          const float* __restrict__ b_ih,
                          const float* __restrict__ b_hh,
                          const float* __restrict__ W_lin,
                          const float* __restrict__ b_lin,
                          float* __restrict__ out,
                          int* __restrict__ flags,
                          float* __restrict__ h_buf)
{
    __shared__ float h_lds[HDIM];      // 8 KiB: h_{t-1}
    __shared__ float s_lds[TSTEPS];    // 16 KiB: src[0,t,0]
    __shared__ float wlin_lds[HDIM];   // 8 KiB: W_lin row

    const int wg   = blockIdx.x;       // 0..255
    const int tid  = threadIdx.x;      // 0..511
    const int wave = tid >> 6;         // unit sub-index u, 0..7
    const int lane = tid & 63;
    const int g    = lane >> 4;        // gate 0..3 (i,f,g,o)
    const int sub  = lane & 15;        // column-slice within row
    const int unit = wg * 8 + wave;    // hidden unit owned by this wave
    const int row  = g * HDIM + unit;  // W_hh row for (unit, gate)

    // ---- one-time init ----
    for (int i = tid; i < TSTEPS; i += NTH) s_lds[i] = src[3 * i];
    for (int i = tid; i < HDIM;   i += NTH) wlin_lds[i] = W_lin[i];
    for (int i = tid; i < HDIM;   i += NTH) h_lds[i] = 0.0f;  // h_{-1} = 0

    const float s01  = src[1];
    const float s02  = src[2];
    const float blin = b_lin[0];

    // per-row constants
    const float w0    = W_ih[row * 3 + 0];
    const float w1    = W_ih[row * 3 + 1];
    const float w2    = W_ih[row * 3 + 2];
    const float w12   = w1 + w2;
    const float braw  = b_ih[row] + b_hh[row];
    const float bfold = braw + w12 * blin;

    // Register-resident folded weights: W'[row,c] = W_hh[row,c] + w12*W_lin[c]
    // This lane's columns: c = k*64 + sub*4 + {0..3}, k = 0..31.
    float wreg[128];
    {
        const float* wrow = W_hh + (size_t)row * HDIM;
        #pragma unroll
        for (int k = 0; k < 32; ++k) {
            const int c = k * 64 + sub * 4;
            float4 wv = *reinterpret_cast<const float4*>(wrow + c);
            float4 lv = *reinterpret_cast<const float4*>(W_lin + c);
            wreg[k * 4 + 0] = wv.x + w12 * lv.x;
            wreg[k * 4 + 1] = wv.y + w12 * lv.y;
            wreg[k * 4 + 2] = wv.z + w12 * lv.z;
            wreg[k * 4 + 3] = wv.w + w12 * lv.w;
        }
    }

    __syncthreads();

    float c_state = 0.0f;  // replicated across the wave's 64 lanes

    for (int t = 0; t < TSTEPS; ++t) {
        // input contribution for this row
        float xterm;
        if (t == 0) {
            // x0 = [src0, src1, src2], h_{-1}=0 (matvec term is 0)
            xterm = braw + w0 * s_lds[0] + w1 * s01 + w2 * s02;
        } else {
            xterm = bfold + w0 * s_lds[t];
        }

        // matvec partial over this lane's 128 columns (4 accumulators for ILP)
        float a0 = 0.0f, a1 = 0.0f, a2 = 0.0f, a3 = 0.0f;
        #pragma unroll
        for (int k = 0; k < 32; ++k) {
            const int c = k * 64 + sub * 4;
            float4 h4 = *reinterpret_cast<const float4*>(&h_lds[c]);
            a0 += wreg[k * 4 + 0] * h4.x;
            a1 += wreg[k * 4 + 1] * h4.y;
            a2 += wreg[k * 4 + 2] * h4.z;
            a3 += wreg[k * 4 + 3] * h4.w;
        }
        float sum = (a0 + a1) + (a2 + a3);
        // reduce across the 16 lanes of this row-group
        sum += __shfl_xor(sum, 1);
        sum += __shfl_xor(sum, 2);
        sum += __shfl_xor(sum, 4);
        sum += __shfl_xor(sum, 8);
        const float gate = sum + xterm;

        // gather i,f,g,o from groups 0..3 of this wave
        const float gi = __shfl(gate, 0);
        const float gf = __shfl(gate, 16);
        const float gg = __shfl(gate, 32);
        const float go = __shfl(gate, 48);
        c_state = sigmoidf_(gf) * c_state + sigmoidf_(gi) * tanhf(gg);
        const float h_new = sigmoidf_(go) * tanhf(c_state);

        const int par = t & 1;
        if (lane == 0) {
            __hip_atomic_store(&h_buf[par * HDIM + unit], h_new,
                               __ATOMIC_RELAXED, __HIP_MEMORY_SCOPE_AGENT);
        }
        __syncthreads();  // compiler drains vmcnt before s_barrier: stores acked
        if (tid == 0) {
            __hip_atomic_store(&flags[wg], t + 1,
                               __ATOMIC_RELAXED, __HIP_MEMORY_SCOPE_AGENT);
        }
        if (wave == 0) {
            const int base = lane * 4;  // 64 lanes x 4 flags = 256
            for (;;) {
                int ok = 1;
                #pragma unroll
                for (int j = 0; j < 4; ++j) {
                    const int f = __hip_atomic_load(
                        &flags[base + j], __ATOMIC_RELAXED,
                        __HIP_MEMORY_SCOPE_AGENT);
                    ok &= (f >= t + 1);
                }
                if (__all(ok)) break;
            }
        }
        __syncthreads();

        // fetch h_t (coherence-point loads; 4 floats/thread)
        {
            const int b = par * HDIM + tid * 4;
            float4 hv;
            hv.x = __hip_atomic_load(&h_buf[b + 0], __ATOMIC_RELAXED, __HIP_MEMORY_SCOPE_AGENT);
            hv.y = __hip_atomic_load(&h_buf[b + 1], __ATOMIC_RELAXED, __HIP_MEMORY_SCOPE_AGENT);
            hv.z = __hip_atomic_load(&h_buf[b + 2], __ATOMIC_RELAXED, __HIP_MEMORY_SCOPE_AGENT);
            hv.w = __hip_atomic_load(&h_buf[b + 3], __ATOMIC_RELAXED, __HIP_MEMORY_SCOPE_AGENT);
            *reinterpret_cast<float4*>(&h_lds[tid * 4]) = hv;
        }
        __syncthreads();

        // y_t = W_lin . h_t + b_lin, by owner WG (t % 256), wave 7
        if (wg == (t & (NWG - 1)) && wave == 7) {
            float ysum = 0.0f;
            #pragma unroll
            for (int k = 0; k < 32; ++k) {
                ysum += wlin_lds[k * 64 + lane] * h_lds[k * 64 + lane];
            }
            ysum += __shfl_xor(ysum, 1);
            ysum += __shfl_xor(ysum, 2);
            ysum += __shfl_xor(ysum, 4);
            ysum += __shfl_xor(ysum, 8);
            ysum += __shfl_xor(ysum, 16);
            ysum += __shfl_xor(ysum, 32);
            if (lane == 0) out[t] = ysum + blin;
        }
    }
}

extern "C" void kernel_launch(void* const* d_in, const int* in_sizes, int n_in,
                              void* d_out, int out_size, void* d_ws, size_t ws_size,
                              hipStream_t stream) {
    const float* src   = (const float*)d_in[0];
    const float* W_ih  = (const float*)d_in[1];
    const float* W_hh  = (const float*)d_in[2];
    const float* b_ih  = (const float*)d_in[3];
    const float* b_hh  = (const float*)d_in[4];
    const float* W_lin = (const float*)d_in[5];
    const float* b_lin = (const float*)d_in[6];
    float* out = (float*)d_out;

    // ws layout: [0,1024): flags (256 ints, zeroed each launch)
    //            [4096, 4096+16 KiB): h_buf double buffer (written every step
    //            before read -> no init needed)
    int*   flags = (int*)d_ws;
    float* h_buf = (float*)((char*)d_ws + 4096);

    hipMemsetAsync(d_ws, 0, 4096, stream);

    void* args[] = { &src, &W_ih, &W_hh, &b_ih, &b_hh, &W_lin, &b_lin,
                     &out, &flags, &h_buf };
    hipLaunchCooperativeKernel((const void*)weld_lstm_persistent,
                               dim3(NWG), dim3(NTH), args, 0, stream);
}